// Round 6
// baseline (274.428 us; speedup 1.0000x reference)
//
#include <hip/hip_runtime.h>
#include <hip/hip_bf16.h>

typedef __bf16 bf16x8 __attribute__((ext_vector_type(8)));
typedef float  f32x4  __attribute__((ext_vector_type(4)));
typedef float  f32x2  __attribute__((ext_vector_type(2)));

#define WBT_STRIDE 136   // LDS bf16/row: 80 rows x 128 k; bank step 4 -> 2-way (free)
#define H1_STRIDE  104   // LDS bf16/row: 128 rows x 96 k; 16B-aligned rows

// workspace layout (bytes)
#define WS_WBT   0u             // bf16 [512][80][128]  (n-major folded W2)  10,485,760
#define WS_QC    10485760u      // f32  [512][80]                               163,840
#define WS_W3T   10649600u      // bf16 [48][96] zero-padded W3^T                 9,216

// ---------------- K1: per-batch prep -----------------
__global__ __launch_bounds__(256)
void k1_prep(const float* __restrict__ query,
             const float* __restrict__ W1, const float* __restrict__ b1,
             const float* __restrict__ alpha,
             const float* __restrict__ W2, const float* __restrict__ b2,
             const float* __restrict__ W3,
             unsigned char* __restrict__ ws)
{
    __shared__ float qy[128];
    __shared__ float qpart[2][128];
    __shared__ float qs[128];
    __shared__ float qcp[2][80];

    const int b = blockIdx.x, t = threadIdx.x;
    __hip_bfloat16* wbt = (__hip_bfloat16*)(ws + WS_WBT);
    float*          qcw = (float*)(ws + WS_QC);
    __hip_bfloat16* w3t = (__hip_bfloat16*)(ws + WS_W3T);

    if (t < 128) qy[t] = query[b * 128 + t];
    __syncthreads();

    {   // q = query @ W1 + b1 (split-K x2)
        const int j = t & 127, kh = t >> 7;
        float acc = (kh == 0) ? b1[j] : 0.0f;
        const float* w1p = W1 + (kh * 64) * 128 + j;
        #pragma unroll 4
        for (int k = 0; k < 64; ++k) acc = fmaf(qy[kh * 64 + k], w1p[k * 128], acc);
        qpart[kh][j] = acc;
    }
    if (b == 0) {   // one-time W3^T zero-padded [48][96]
        for (int e = t; e < 48 * 96; e += 256) {
            int j = e / 96, k = e % 96;
            float v = (j < 40 && k < 80) ? W3[k * 40 + j] : 0.0f;
            w3t[e] = __hip_bfloat16(v);
        }
    }
    __syncthreads();
    if (t < 128) {
        float s = qpart[0][t] + qpart[1][t];
        float a = alpha[t];
        qs[t] = (s >= 0.0f) ? s : a * s;
    }
    __syncthreads();

    // qconst[j] = q @ (W2a + W2c) + b2  (split-K x2)
    if (t < 160) {
        const int jj = (t < 80) ? t : t - 80;
        const int hh = (t < 80) ? 0 : 1;
        float acc = (hh == 0) ? b2[jj] : 0.0f;
        #pragma unroll 4
        for (int k = hh * 64; k < hh * 64 + 64; ++k)
            acc = fmaf(qs[k], W2[k * 80 + jj] + W2[(256 + k) * 80 + jj], acc);
        qcp[hh][jj] = acc;
    }
    // fold: wbt[b][n][k] = (W2b - W2c + q_k * W2d)[k][n]   (b128 writes, coalesced)
    for (int e = t; e < 80 * 16; e += 256) {
        const int n = e >> 4, c = e & 15;
        bf16x8 v;
        #pragma unroll
        for (int j = 0; j < 8; ++j) {
            const int k = c * 8 + j;
            float w = W2[(128 + k) * 80 + n] - W2[(256 + k) * 80 + n]
                    + qs[k] * W2[(384 + k) * 80 + n];
            v[j] = (__bf16)w;
        }
        *(bf16x8*)&wbt[(size_t)b * 10240 + n * 128 + c * 8] = v;
    }
    __syncthreads();
    if (t < 80) qcw[b * 80 + t] = qcp[0][t] + qcp[1][t];
}

// ---------------- K2: fused scores + softmax + weighted sum -----------------
__global__ __launch_bounds__(512, 4)
void k2_main(const float* __restrict__ facts,
             const int*   __restrict__ mask,
             const float* __restrict__ W4, const float* __restrict__ b3,
             const unsigned char* __restrict__ ws,
             float* __restrict__ out)
{
    __shared__ __align__(16) __bf16 WbT[80 * WBT_STRIDE];    // folded W2, [n][k]
    __shared__ __align__(16) __bf16 h1all[128 * H1_STRIDE];  // per-wave 16-row slabs
    __shared__ float qcs[80];
    __shared__ float w4s[48], b3s[48];
    __shared__ float scores[512];
    __shared__ float Zw[8];

    const int b = blockIdx.x, t = threadIdx.x;
    const int wave = t >> 6, lane = t & 63, qd = lane >> 4, m = lane & 15;
    const float* fb = facts + (size_t)b * (512 * 128);
    const int*   mb = mask + b * 512;

    const __hip_bfloat16* wbt_g = (const __hip_bfloat16*)(ws + WS_WBT) + (size_t)b * 10240;
    const float*          qcw   = (const float*)(ws + WS_QC) + b * 80;
    const __bf16*         w3t_g = (const __bf16*)(ws + WS_W3T);

    // tile-0 facts + all mask loads issued first (in flight through staging)
    f32x4 av0[4][2];
    int mv[4];
    {
        const float* p0 = &fb[(size_t)(wave * 64 + m) * 128 + qd * 8];
        #pragma unroll
        for (int kc = 0; kc < 4; ++kc) {
            av0[kc][0] = *(const f32x4*)(p0 + kc * 32);
            av0[kc][1] = *(const f32x4*)(p0 + kc * 32 + 4);
        }
        #pragma unroll
        for (int tl = 0; tl < 4; ++tl) mv[tl] = mb[wave * 64 + tl * 16 + m];
    }

    // stage WbT from ws (coalesced b128), small vectors, h1 pad cols
    for (int e = t; e < 80 * 16; e += 512) {
        const int n = e >> 4, c = e & 15;
        bf16x8 v = *(const bf16x8*)&wbt_g[n * 128 + c * 8];
        *(bf16x8*)&WbT[n * WBT_STRIDE + c * 8] = v;
    }
    for (int e = t; e < 128 * 16; e += 512) {                // h1 cols 80..95 := 0
        int r = e >> 4, c = 80 + (e & 15);
        h1all[r * H1_STRIDE + c] = (__bf16)0.0f;
    }
    if (t < 80) qcs[t] = qcw[t];
    if (t < 48) { w4s[t] = (t < 40) ? W4[t] : 0.f; b3s[t] = (t < 40) ? b3[t] : 0.f; }
    __syncthreads();

    __bf16* h1w = &h1all[wave * 16 * H1_STRIDE];

    #pragma unroll
    for (int tile = 0; tile < 4; ++tile) {
        const int s0 = wave * 64 + tile * 16;

        f32x4 av[4][2];
        if (tile == 0) {
            #pragma unroll
            for (int kc = 0; kc < 4; ++kc) { av[kc][0] = av0[kc][0]; av[kc][1] = av0[kc][1]; }
        } else {
            const float* p0 = &fb[(size_t)(s0 + m) * 128 + qd * 8];
            #pragma unroll
            for (int kc = 0; kc < 4; ++kc) {
                av[kc][0] = *(const f32x4*)(p0 + kc * 32);
                av[kc][1] = *(const f32x4*)(p0 + kc * 32 + 4);
            }
        }
        bf16x8 af[4];
        #pragma unroll
        for (int kc = 0; kc < 4; ++kc)
            #pragma unroll
            for (int i = 0; i < 8; ++i)
                af[kc][i] = (__bf16)((i < 4) ? av[kc][0][i] : av[kc][1][i - 4]);

        // GEMM1: [16,128]@[128,80] -> sigmoid -> h1 (wave-private LDS slab)
        #pragma unroll
        for (int ct = 0; ct < 5; ++ct) {
            f32x4 acc = {0.f, 0.f, 0.f, 0.f};
            const int n1 = ct * 16 + m;
            #pragma unroll
            for (int kc = 0; kc < 4; ++kc) {
                bf16x8 bfr = *(const bf16x8*)&WbT[n1 * WBT_STRIDE + kc * 32 + qd * 8];
                acc = __builtin_amdgcn_mfma_f32_16x16x32_bf16(af[kc], bfr, acc, 0, 0, 0);
            }
            const float qc = qcs[n1];
            #pragma unroll
            for (int r = 0; r < 4; ++r) {
                float x = acc[r] + qc;
                float h = __builtin_amdgcn_rcpf(1.0f + __expf(-x));
                h1w[(qd * 4 + r) * H1_STRIDE + n1] = (__bf16)h;
            }
        }
        asm volatile("s_waitcnt lgkmcnt(0)" ::: "memory");   // wave-private: no barrier

        // GEMM2: [16,96]@[96,48]; B-frags streamed from ws (L1/L2-hot 9 KB)
        bf16x8 a2[3];
        #pragma unroll
        for (int kc = 0; kc < 3; ++kc)
            a2[kc] = *(const bf16x8*)&h1w[m * H1_STRIDE + kc * 32 + qd * 8];
        float sc[4] = {0.f, 0.f, 0.f, 0.f};
        #pragma unroll 1
        for (int ct = 0; ct < 3; ++ct) {
            f32x4 acc2 = {0.f, 0.f, 0.f, 0.f};
            #pragma unroll
            for (int kc = 0; kc < 3; ++kc) {
                bf16x8 bfr = *(const bf16x8*)&w3t_g[(ct * 16 + m) * 96 + kc * 32 + qd * 8];
                acc2 = __builtin_amdgcn_mfma_f32_16x16x32_bf16(a2[kc], bfr, acc2, 0, 0, 0);
            }
            const int col = ct * 16 + m;
            const float w4v = w4s[col], b3v = b3s[col];
            #pragma unroll
            for (int r = 0; r < 4; ++r) {
                float h2 = __builtin_amdgcn_rcpf(1.0f + __expf(-(acc2[r] + b3v)));
                sc[r] = fmaf(h2, w4v, sc[r]);
            }
        }
        #pragma unroll
        for (int d = 1; d < 16; d <<= 1)
            #pragma unroll
            for (int r = 0; r < 4; ++r)
                sc[r] += __shfl_xor(sc[r], d);

        // own-row score via bpermute (row m lives as sc[m&3] in quad m>>2)
        const int idx = ((((m >> 2) << 4) | m) << 2);
        float s0v = __int_as_float(__builtin_amdgcn_ds_bpermute(idx, __float_as_int(sc[0])));
        float s1v = __int_as_float(__builtin_amdgcn_ds_bpermute(idx, __float_as_int(sc[1])));
        float s2v = __int_as_float(__builtin_amdgcn_ds_bpermute(idx, __float_as_int(sc[2])));
        float s3v = __int_as_float(__builtin_amdgcn_ds_bpermute(idx, __float_as_int(sc[3])));
        const int rr = m & 3;
        float srow = (rr == 0) ? s0v : (rr == 1) ? s1v : (rr == 2) ? s2v : s3v;

        // p = mask ? exp(score) : 0  (|score| <= sum|W4| ~ 5; b4 cancels in softmax)
        const float pm = (mv[tile] == 1) ? __expf(srow) : 0.f;
        if (lane < 16) scores[s0 + lane] = pm;
    }
    __syncthreads();

    // Z: one score per thread -> wave reduce -> block sum
    float z = scores[t];
    #pragma unroll
    for (int d = 1; d < 64; d <<= 1) z += __shfl_xor(z, d);
    if (lane == 0) Zw[wave] = z;

    // phase E: wave w sums rows [64w,64w+64); lane covers cols {2l, 2l+1} (coalesced)
    float a0 = 0.f, a1 = 0.f;
    {
        const float* rp = fb + (size_t)(wave * 64) * 128 + 2 * lane;
        const float* pp = &scores[wave * 64];
        #pragma unroll 8
        for (int s = 0; s < 64; ++s) {
            f32x2 v = *(const f32x2*)(rp + (size_t)s * 128);
            const float p = pp[s];
            a0 = fmaf(p, v[0], a0);
            a1 = fmaf(p, v[1], a1);
        }
    }
    float* outw = (float*)h1all;       // h1 slabs dead; reuse as [8][128] partials
    __syncthreads();                   // Zw written; h1all safe to overwrite
    outw[wave * 128 + 2 * lane]     = a0;
    outw[wave * 128 + 2 * lane + 1] = a1;
    __syncthreads();

    if (t < 128) {
        float Zg = 0.f, v = 0.f;
        #pragma unroll
        for (int w = 0; w < 8; ++w) { v += outw[w * 128 + t]; Zg += Zw[w]; }
        out[b * 128 + t] = v / Zg;
    }
}

extern "C" void kernel_launch(void* const* d_in, const int* in_sizes, int n_in,
                              void* d_out, int out_size, void* d_ws, size_t ws_size,
                              hipStream_t stream) {
    (void)in_sizes; (void)n_in; (void)ws_size; (void)out_size;
    const float* query = (const float*)d_in[0];
    const float* facts = (const float*)d_in[1];
    const int*   mask  = (const int*)d_in[2];
    const float* W1 = (const float*)d_in[3];
    const float* b1 = (const float*)d_in[4];
    const float* al = (const float*)d_in[5];
    const float* W2 = (const float*)d_in[6];
    const float* b2 = (const float*)d_in[7];
    const float* W3 = (const float*)d_in[8];
    const float* b3 = (const float*)d_in[9];
    const float* W4 = (const float*)d_in[10];
    const float* b4 = (const float*)d_in[11];
    (void)b4;  // cancels under softmax
    unsigned char* ws = (unsigned char*)d_ws;

    k1_prep<<<dim3(512), dim3(256), 0, stream>>>(query, W1, b1, al, W2, b2, W3, ws);
    k2_main<<<dim3(512), dim3(512), 0, stream>>>(facts, mask, W4, b3, ws, (float*)d_out);
}

// Round 7
// 234.222 us; speedup vs baseline: 1.1717x; 1.1717x over previous
//
#include <hip/hip_runtime.h>
#include <hip/hip_bf16.h>

typedef __bf16 bf16x8 __attribute__((ext_vector_type(8)));
typedef float  f32x4  __attribute__((ext_vector_type(4)));
typedef float  f32x2  __attribute__((ext_vector_type(2)));

#define WBT_STRIDE 136   // bf16/row: 80 rows x 128 k; 272B rows (16B-aligned, 2-way banks)
#define H1_STRIDE  104   // bf16/row: 128 rows x 96 k
#define W3T_STRIDE 104   // bf16/row: 48 rows x 96 k

__global__ __launch_bounds__(512, 4)
void attn_fused(const float* __restrict__ query,
                const float* __restrict__ facts,
                const int*   __restrict__ mask,
                const float* __restrict__ W1, const float* __restrict__ b1,
                const float* __restrict__ alpha,
                const float* __restrict__ W2, const float* __restrict__ b2,
                const float* __restrict__ W3, const float* __restrict__ b3,
                const float* __restrict__ W4,
                float* __restrict__ out)
{
    __shared__ __align__(16) __bf16 WbT[80 * WBT_STRIDE];    // folded W2, [n][k]
    __shared__ __align__(16) __bf16 W3T[48 * W3T_STRIDE];    // W3^T zero-padded
    __shared__ __align__(16) __bf16 h1all[128 * H1_STRIDE];  // per-wave 16-row slabs
    __shared__ float qy[128], qs[128], qcs[80];
    __shared__ float qpart[4][128], qcp[4][80];
    __shared__ float w4s[48], b3s[48];
    __shared__ float scores[512];
    __shared__ float Zw[8];

    const int b = blockIdx.x, t = threadIdx.x;
    const int wave = t >> 6, lane = t & 63, qd = lane >> 4, m = lane & 15;
    const float* fb = facts + (size_t)b * (512 * 128);
    const int*   mb = mask + b * 512;

    // ---- tile-0 facts + all mask loads issued FIRST (in flight all prologue) ----
    f32x4 av[2][4][2];
    int mv[4];
    {
        const float* p0 = &fb[(size_t)(wave * 64 + m) * 128 + qd * 8];
        #pragma unroll
        for (int kc = 0; kc < 4; ++kc) {
            av[0][kc][0] = *(const f32x4*)(p0 + kc * 32);
            av[0][kc][1] = *(const f32x4*)(p0 + kc * 32 + 4);
        }
        #pragma unroll
        for (int tl = 0; tl < 4; ++tl) mv[tl] = mb[wave * 64 + tl * 16 + m];
    }

    // ---- prologue (R4-identical): query, W3^T, h1 pad cols, small vecs ----
    if (t < 128) qy[t] = query[b * 128 + t];
    for (int e = t; e < 48 * 96; e += 512) {
        int j = e / 96, k = e % 96;                          // W3 row-major [80][40]
        W3T[j * W3T_STRIDE + k] = (j < 40 && k < 80) ? (__bf16)W3[k * 40 + j]
                                                     : (__bf16)0.0f;
    }
    for (int e = t; e < 128 * 16; e += 512) {                // h1 cols 80..95 := 0
        int r = e >> 4, c = 80 + (e & 15);
        h1all[r * H1_STRIDE + c] = (__bf16)0.0f;
    }
    if (t < 48) { w4s[t] = (t < 40) ? W4[t] : 0.f; b3s[t] = (t < 40) ? b3[t] : 0.f; }
    __syncthreads();

    // q = PReLU(query @ W1 + b1), split-K x4
    {
        int j = t & 127, kh = t >> 7;
        float acc = (kh == 0) ? b1[j] : 0.f;
        const float* w1p = W1 + (kh * 32) * 128 + j;
        #pragma unroll 8
        for (int k = 0; k < 32; ++k) acc = fmaf(qy[kh * 32 + k], w1p[k * 128], acc);
        qpart[kh][j] = acc;
    }
    __syncthreads();
    if (t < 128) {
        float s = (qpart[0][t] + qpart[1][t]) + (qpart[2][t] + qpart[3][t]);
        qs[t] = (s >= 0.f) ? s : alpha[t] * s;
    }
    __syncthreads();

    // qconst = q@(W2a+W2c)+b2 (split-K x4); fold WbT[n][k] = W2b - W2c + q_k*W2d
    if (t < 320) {
        int jj = t % 80, hh = t / 80;
        float acc = (hh == 0) ? b2[jj] : 0.f;
        #pragma unroll 8
        for (int k = hh * 32; k < hh * 32 + 32; ++k)
            acc = fmaf(qs[k], W2[k * 80 + jj] + W2[(256 + k) * 80 + jj], acc);
        qcp[hh][jj] = acc;
    }
    for (int e = t; e < 128 * 80; e += 512) {                // coalesced W2 reads
        int k = e / 80, n = e - k * 80;
        float w = W2[(128 + k) * 80 + n] - W2[(256 + k) * 80 + n]
                + qs[k] * W2[(384 + k) * 80 + n];
        WbT[n * WBT_STRIDE + k] = (__bf16)w;
    }
    __syncthreads();
    if (t < 80) qcs[t] = (qcp[0][t] + qcp[1][t]) + (qcp[2][t] + qcp[3][t]);
    __syncthreads();

    // ---- main: 4 tiles, distance-1 double-buffered facts prefetch ----
    __bf16* h1w = &h1all[wave * 16 * H1_STRIDE];

    #pragma unroll
    for (int tile = 0; tile < 4; ++tile) {
        const int p = tile & 1;

        // prefetch next tile FIRST — in flight through this tile's whole body
        if (tile < 3) {
            const float* pn = &fb[(size_t)(wave * 64 + (tile + 1) * 16 + m) * 128 + qd * 8];
            #pragma unroll
            for (int kc = 0; kc < 4; ++kc) {
                av[1 - p][kc][0] = *(const f32x4*)(pn + kc * 32);
                av[1 - p][kc][1] = *(const f32x4*)(pn + kc * 32 + 4);
            }
        }

        bf16x8 af[4];
        #pragma unroll
        for (int kc = 0; kc < 4; ++kc)
            #pragma unroll
            for (int i = 0; i < 8; ++i)
                af[kc][i] = (__bf16)((i < 4) ? av[p][kc][0][i] : av[p][kc][1][i - 4]);

        // GEMM1: [16,128]@[128,80] -> sigmoid -> h1 (wave-private LDS slab)
        #pragma unroll
        for (int ct = 0; ct < 5; ++ct) {
            f32x4 acc = {0.f, 0.f, 0.f, 0.f};
            const int n1 = ct * 16 + m;
            #pragma unroll
            for (int kc = 0; kc < 4; ++kc) {
                bf16x8 bfr = *(const bf16x8*)&WbT[n1 * WBT_STRIDE + kc * 32 + qd * 8];
                acc = __builtin_amdgcn_mfma_f32_16x16x32_bf16(af[kc], bfr, acc, 0, 0, 0);
            }
            const float qc = qcs[n1];
            #pragma unroll
            for (int r = 0; r < 4; ++r) {
                float x = acc[r] + qc;
                float h = __builtin_amdgcn_rcpf(1.0f + __expf(-x));
                h1w[(qd * 4 + r) * H1_STRIDE + n1] = (__bf16)h;
            }
        }
        asm volatile("s_waitcnt lgkmcnt(0)" ::: "memory");   // wave-private: no barrier

        // GEMM2: [16,96]@[96,48] -> sigmoid -> score = h2 @ W4
        bf16x8 a2[3];
        #pragma unroll
        for (int kc = 0; kc < 3; ++kc)
            a2[kc] = *(const bf16x8*)&h1w[m * H1_STRIDE + kc * 32 + qd * 8];
        float sc[4] = {0.f, 0.f, 0.f, 0.f};
        #pragma unroll
        for (int ct = 0; ct < 3; ++ct) {
            f32x4 acc2 = {0.f, 0.f, 0.f, 0.f};
            #pragma unroll
            for (int kc = 0; kc < 3; ++kc) {
                bf16x8 bfr = *(const bf16x8*)&W3T[(ct * 16 + m) * W3T_STRIDE + kc * 32 + qd * 8];
                acc2 = __builtin_amdgcn_mfma_f32_16x16x32_bf16(a2[kc], bfr, acc2, 0, 0, 0);
            }
            const int col = ct * 16 + m;
            const float w4v = w4s[col], b3v = b3s[col];
            #pragma unroll
            for (int r = 0; r < 4; ++r) {
                float h2 = __builtin_amdgcn_rcpf(1.0f + __expf(-(acc2[r] + b3v)));
                sc[r] = fmaf(h2, w4v, sc[r]);
            }
        }
        #pragma unroll
        for (int d = 1; d < 16; d <<= 1)
            #pragma unroll
            for (int r = 0; r < 4; ++r)
                sc[r] += __shfl_xor(sc[r], d);

        // own-row score via bpermute (row m lives as sc[m&3] in quad m>>2)
        const int idx = ((((m >> 2) << 4) | m) << 2);
        float s0v = __int_as_float(__builtin_amdgcn_ds_bpermute(idx, __float_as_int(sc[0])));
        float s1v = __int_as_float(__builtin_amdgcn_ds_bpermute(idx, __float_as_int(sc[1])));
        float s2v = __int_as_float(__builtin_amdgcn_ds_bpermute(idx, __float_as_int(sc[2])));
        float s3v = __int_as_float(__builtin_amdgcn_ds_bpermute(idx, __float_as_int(sc[3])));
        const int rr = m & 3;
        float srow = (rr == 0) ? s0v : (rr == 1) ? s1v : (rr == 2) ? s2v : s3v;

        // p = mask ? exp(score) : 0  (|score| <= sum|W4| ~ 5; b4 cancels in softmax)
        const float pm = (mv[tile] == 1) ? __expf(srow) : 0.f;
        if (lane < 16) scores[wave * 64 + tile * 16 + lane] = pm;
    }
    __syncthreads();

    // ---- Z: one score per thread -> wave reduce -> per-wave partials ----
    float z = scores[t];
    #pragma unroll
    for (int d = 1; d < 64; d <<= 1) z += __shfl_xor(z, d);
    if (lane == 0) Zw[wave] = z;

    // ---- phase E: wave w re-reads rows [64w,64w+64) (L2/L3-hot), coalesced ----
    float a0 = 0.f, a1 = 0.f;
    {
        const float* rp = fb + (size_t)(wave * 64) * 128 + 2 * lane;
        const float* pp = &scores[wave * 64];
        #pragma unroll 8
        for (int s = 0; s < 64; ++s) {
            f32x2 v = *(const f32x2*)(rp + (size_t)s * 128);
            const float p = pp[s];
            a0 = fmaf(p, v[0], a0);
            a1 = fmaf(p, v[1], a1);
        }
    }
    float* outw = (float*)h1all;       // h1 slabs dead past the barrier above
    __syncthreads();                   // Zw visible; safe to overwrite h1all
    outw[wave * 128 + 2 * lane]     = a0;
    outw[wave * 128 + 2 * lane + 1] = a1;
    __syncthreads();

    if (t < 128) {
        float Zg = 0.f, v = 0.f;
        #pragma unroll
        for (int w = 0; w < 8; ++w) { v += outw[w * 128 + t]; Zg += Zw[w]; }
        out[b * 128 + t] = v / Zg;
    }
}

extern "C" void kernel_launch(void* const* d_in, const int* in_sizes, int n_in,
                              void* d_out, int out_size, void* d_ws, size_t ws_size,
                              hipStream_t stream) {
    (void)in_sizes; (void)n_in; (void)d_ws; (void)ws_size; (void)out_size;
    const float* query = (const float*)d_in[0];
    const float* facts = (const float*)d_in[1];
    const int*   mask  = (const int*)d_in[2];
    const float* W1 = (const float*)d_in[3];
    const float* b1 = (const float*)d_in[4];
    const float* al = (const float*)d_in[5];
    const float* W2 = (const float*)d_in[6];
    const float* b2 = (const float*)d_in[7];
    const float* W3 = (const float*)d_in[8];
    const float* b3 = (const float*)d_in[9];
    const float* W4 = (const float*)d_in[10];
    const float* b4 = (const float*)d_in[11];
    (void)b4;  // cancels under softmax
    attn_fused<<<dim3(512), dim3(512), 0, stream>>>(
        query, facts, mask, W1, b1, al, W2, b2, W3, b3, W4, (float*)d_out);
}